// Round 5
// baseline (357.403 us; speedup 1.0000x reference)
//
#include <hip/hip_runtime.h>

typedef unsigned short ushort_t;
typedef __attribute__((ext_vector_type(8))) short bf8_t;   // 8 x bf16 (4 VGPRs)
typedef __attribute__((ext_vector_type(4))) float f4_t;    // MFMA acc

#define B_   4096
#define IN_  1024
#define H_   1024
#define F_   128
#define G4_  4096
#define EPS_ 1e-5f

__device__ __forceinline__ float us2f(unsigned short s) {
  union { unsigned int u; float f; } v;
  v.u = ((unsigned int)s) << 16;
  return v.f;
}
__device__ __forceinline__ unsigned short f2us(float f) {  // fp32 -> bf16 RNE
  union { float f; unsigned int u; } v;
  v.f = f;
  unsigned int r = (v.u + 0x7fffu + ((v.u >> 16) & 1u)) >> 16;
  return (unsigned short)r;
}
__device__ __forceinline__ float sigf(float x) { return 1.0f / (1.0f + __expf(-x)); }
__device__ __forceinline__ float tanh_f(float x) { return 1.0f - 2.0f / (1.0f + __expf(2.0f * x)); }

// Runtime input-dtype detection (R1/R2 A/B proved fp32; keep as insurance).
__device__ __forceinline__ int detect_fp32(const void* disc) {
  return ((const unsigned int*)disc)[0] == 0x3F800000u;
}
__device__ __forceinline__ float ldf(const void* p, int i, int fp32) {
  return fp32 ? ((const float*)p)[i] : us2f(((const ushort_t*)p)[i]);
}
__device__ __forceinline__ void ld8(const void* p, int idx, float* o, int fp32) {
  if (fp32) {
    const float4* q = (const float4*)((const float*)p + idx);
    float4 v0 = q[0], v1 = q[1];
    o[0]=v0.x; o[1]=v0.y; o[2]=v0.z; o[3]=v0.w;
    o[4]=v1.x; o[5]=v1.y; o[6]=v1.z; o[7]=v1.w;
  } else {
    uint4 v = *(const uint4*)((const ushort_t*)p + idx);
    const ushort_t* pv = (const ushort_t*)&v;
    #pragma unroll
    for (int i = 0; i < 8; i++) o[i] = us2f(pv[i]);
  }
}
__device__ __forceinline__ bf8_t cvt8(const float* f) {
  bf8_t r;
  #pragma unroll
  for (int i = 0; i < 8; i++) r[i] = (short)f2us(f[i]);
  return r;
}

// ---------------------------------------------------------------------------
// K_prep: wb B-frags (as R4 k_prepw) + colsum partials (merged k_colsum).
//   wb[t*4096 + c*512 + l*8 + j] = W[c*32+(l>>4)*8+j][t*16+(l&15)]
//   W[k][n]: k<128 -> w_ih_a[n][k]*ln_i_w[n]; else w_hh_a[n][k-128]*ln_h_w[n]
//   cm[f] += sum of this block's 16 n-rows of raw A[n][f]
// ---------------------------------------------------------------------------
__global__ __launch_bounds__(256) void k_prep(
    const void* __restrict__ Ai, const void* __restrict__ Ah,
    const void* __restrict__ lnwi, const void* __restrict__ lnwh,
    ushort_t* __restrict__ wb,
    float* __restrict__ cm_i, float* __restrict__ cm_h)
{
  int t = blockIdx.x, tid = threadIdx.x;
  int fp32 = detect_fp32(lnwi);
  #pragma unroll
  for (int i = 0; i < 16; i++) {
    int e = i * 256 + tid;
    int c = e >> 9, l = (e >> 3) & 63, j = e & 7;
    int k = c * 32 + ((l >> 4) << 3) + j;
    int n = t * 16 + (l & 15);
    float v;
    if (k < 128) v = ldf(Ai, n * F_ + k, fp32) * ldf(lnwi, n, fp32);
    else         v = ldf(Ah, n * F_ + (k - 128), fp32) * ldf(lnwh, n, fp32);
    wb[(size_t)t * 4096 + e] = f2us(v);
  }
  // colsum partial: thread tid<128 -> cm_i[f], else cm_h[f-128]
  const void* A = (tid < 128) ? Ai : Ah;
  float* cm = (tid < 128) ? cm_i : cm_h;
  int f = tid & 127;
  float s = 0.f;
  #pragma unroll
  for (int i = 0; i < 16; i++) s += ldf(A, (t * 16 + i) * F_ + f, fp32);
  atomicAdd(&cm[f], s);
}

// ---------------------------------------------------------------------------
// K1 v2 (MFMA): C[b][f] = (sum_k X[b][k]*W[f][k]) * scale(b,f)
// Block = 256 thr = 4 waves; wave = 16 rows x 128 cols; K=1024 (32 kc).
// No LDS: A/B frags loaded directly (quads of a row form full 128-B lines).
// grid (64, 2).
// ---------------------------------------------------------------------------
__global__ __launch_bounds__(256) void k_gemm1(
    const void* __restrict__ X0, const void* __restrict__ X1,
    const void* __restrict__ W0, const void* __restrict__ W1,
    const void* __restrict__ topic,
    const void* __restrict__ thw0, const void* __restrict__ thw1,
    const void* __restrict__ thb0, const void* __restrict__ thb1,
    const void* __restrict__ wb0,  const void* __restrict__ wb1,
    const void* __restrict__ disc,
    float* __restrict__ C0, float* __restrict__ C1)
{
  const void* X   = blockIdx.y ? X1 : X0;
  const void* W   = blockIdx.y ? W1 : W0;
  const void* thw = blockIdx.y ? thw1 : thw0;
  const void* thb = blockIdx.y ? thb1 : thb0;
  const void* wbp = blockIdx.y ? wb1 : wb0;
  float* C = blockIdx.y ? C1 : C0;
  int fp32 = detect_fp32(disc);

  int tid = threadIdx.x;
  int lane = tid & 63, w = tid >> 6;
  int quad = lane >> 4, lcol = lane & 15;
  int brow0 = blockIdx.x * 64 + w * 16;

  f4_t acc[8];
  #pragma unroll
  for (int tf = 0; tf < 8; tf++) acc[tf] = (f4_t){0.f, 0.f, 0.f, 0.f};

  #pragma unroll 2
  for (int kc = 0; kc < 32; kc++) {
    int kb = kc * 32 + quad * 8;
    float a[8];
    ld8(X, (brow0 + lcol) * IN_ + kb, a, fp32);
    bf8_t af = cvt8(a);
    #pragma unroll
    for (int tf = 0; tf < 8; tf++) {
      float bt[8];
      ld8(W, (tf * 16 + lcol) * IN_ + kb, bt, fp32);
      bf8_t bf = cvt8(bt);
      acc[tf] = __builtin_amdgcn_mfma_f32_16x16x32_bf16(af, bf, acc[tf], 0, 0, 0);
    }
  }

  // epilogue: scale(b,f) = sum_t (thb[t] + sum_t' topic[b][t']*thw[t][t']) * wbp[f][t]
  float thwf[3][3], thbf[3];
  #pragma unroll
  for (int t = 0; t < 3; t++) {
    thbf[t] = ldf(thb, t, fp32);
    #pragma unroll
    for (int t2 = 0; t2 < 3; t2++) thwf[t][t2] = ldf(thw, t * 3 + t2, fp32);
  }
  float tmpv[4][3];
  #pragma unroll
  for (int reg = 0; reg < 4; reg++) {
    int b = brow0 + quad * 4 + reg;
    float tp0 = ldf(topic, b * 3 + 0, fp32);
    float tp1 = ldf(topic, b * 3 + 1, fp32);
    float tp2 = ldf(topic, b * 3 + 2, fp32);
    #pragma unroll
    for (int t = 0; t < 3; t++)
      tmpv[reg][t] = thbf[t] + tp0 * thwf[t][0] + tp1 * thwf[t][1] + tp2 * thwf[t][2];
  }
  #pragma unroll
  for (int tf = 0; tf < 8; tf++) {
    int f = tf * 16 + lcol;
    float wv0 = ldf(wbp, f * 3 + 0, fp32);
    float wv1 = ldf(wbp, f * 3 + 1, fp32);
    float wv2 = ldf(wbp, f * 3 + 2, fp32);
    #pragma unroll
    for (int reg = 0; reg < 4; reg++) {
      float sc = tmpv[reg][0] * wv0 + tmpv[reg][1] * wv1 + tmpv[reg][2] * wv2;
      C[(brow0 + quad * 4 + reg) * F_ + f] = acc[tf][reg] * sc;
    }
  }
}

// ---------------------------------------------------------------------------
// K3: Gram G = A^T A  ([128][128]), split-K over n with atomic reduce.
// ---------------------------------------------------------------------------
__global__ __launch_bounds__(256) void k_gram(
    const void* __restrict__ A0, const void* __restrict__ A1,
    const void* __restrict__ disc,
    float* __restrict__ G0, float* __restrict__ G1)
{
  const void* A = blockIdx.y ? A1 : A0;
  float* G = blockIdx.y ? G1 : G0;
  int fp32 = detect_fp32(disc);
  __shared__ float As[32][128];
  int tid = threadIdx.x;
  int f1_0 = blockIdx.x * 32;
  int tf2 = tid & 31, tf1 = tid >> 5;
  float acc[4][4] = {};
  int nbase = blockIdx.z * 256;
  for (int n0 = nbase; n0 < nbase + 256; n0 += 32) {
    #pragma unroll
    for (int j = 0; j < 2; j++) {
      int idx = tid + 256 * j;
      int nn = idx >> 4, f8 = (idx & 15) * 8;
      float t[8];
      ld8(A, (n0 + nn) * F_ + f8, t, fp32);
      #pragma unroll
      for (int i = 0; i < 8; i++) As[nn][f8 + i] = t[i];
    }
    __syncthreads();
    #pragma unroll 4
    for (int nn = 0; nn < 32; nn++) {
      float4 a1 = *(const float4*)&As[nn][f1_0 + 4 * tf1];
      float4 a2 = *(const float4*)&As[nn][4 * tf2];
      const float* x1 = (const float*)&a1;
      const float* x2 = (const float*)&a2;
      #pragma unroll
      for (int i = 0; i < 4; i++)
        #pragma unroll
        for (int j = 0; j < 4; j++) acc[i][j] += x1[i] * x2[j];
    }
    __syncthreads();
  }
  #pragma unroll
  for (int i = 0; i < 4; i++)
    #pragma unroll
    for (int j = 0; j < 4; j++)
      atomicAdd(&G[(f1_0 + 4 * tf1 + i) * F_ + 4 * tf2 + j], acc[i][j]);
}

// ---------------------------------------------------------------------------
// K4: H = C @ G   ([4096][128] @ [128][128])
// ---------------------------------------------------------------------------
__global__ __launch_bounds__(256) void k_gemm2(
    const float* __restrict__ C0, const float* __restrict__ C1,
    const float* __restrict__ Gi, const float* __restrict__ Gh,
    float* __restrict__ H0, float* __restrict__ H1)
{
  const float* C = blockIdx.y ? C1 : C0;
  const float* G = blockIdx.y ? Gh : Gi;
  float* Ho = blockIdx.y ? H1 : H0;
  __shared__ float Xs[32][36];
  __shared__ float Ws[32][132];
  int tid = threadIdx.x, tx = tid & 31, ty = tid >> 5;
  int b0 = blockIdx.x * 32;
  float acc[4][4] = {};
  for (int k0 = 0; k0 < F_; k0 += 32) {
    {
      int r = tid >> 3, k4 = (tid & 7) * 4;
      float4 v = *(const float4*)(C + (b0 + r) * F_ + k0 + k4);
      Xs[k4][r] = v.x; Xs[k4 + 1][r] = v.y; Xs[k4 + 2][r] = v.z; Xs[k4 + 3][r] = v.w;
    }
    #pragma unroll
    for (int j = 0; j < 4; j++) {
      int idx = tid + 256 * j;
      int f = idx >> 3, k4 = (idx & 7) * 4;
      float4 v = *(const float4*)(G + f * F_ + k0 + k4);
      Ws[k4][f] = v.x; Ws[k4 + 1][f] = v.y; Ws[k4 + 2][f] = v.z; Ws[k4 + 3][f] = v.w;
    }
    __syncthreads();
    #pragma unroll 4
    for (int kk = 0; kk < 32; kk++) {
      float4 xv = *(const float4*)&Xs[kk][4 * ty];
      float4 wv = *(const float4*)&Ws[kk][4 * tx];
      const float* xa = (const float*)&xv;
      const float* wa = (const float*)&wv;
      #pragma unroll
      for (int i = 0; i < 4; i++)
        #pragma unroll
        for (int j = 0; j < 4; j++) acc[i][j] += xa[i] * wa[j];
    }
    __syncthreads();
  }
  #pragma unroll
  for (int i = 0; i < 4; i++)
    #pragma unroll
    for (int j = 0; j < 4; j++)
      Ho[(b0 + 4 * ty + i) * F_ + 4 * tx + j] = acc[i][j];
}

// ---------------------------------------------------------------------------
// K5: per-row LN stats via Gram trick; write X in bf16 A-fragment order.
// ---------------------------------------------------------------------------
__global__ __launch_bounds__(256) void k_stats(
    const float* __restrict__ Ca, const float* __restrict__ Cb,
    const float* __restrict__ Ha, const float* __restrict__ Hb,
    const float* __restrict__ cma, const float* __restrict__ cmb,
    float* __restrict__ mrsa, float* __restrict__ mrsb,
    ushort_t* __restrict__ xb)
{
  const float* C  = blockIdx.y ? Cb : Ca;
  const float* Hm = blockIdx.y ? Hb : Ha;
  const float* cm = blockIdx.y ? cmb : cma;
  float* mrs = blockIdx.y ? mrsb : mrsa;
  int kbase = blockIdx.y ? 128 : 0;

  int tid = threadIdx.x;
  int b0 = blockIdx.x * 16;
  int r = tid >> 4, l = tid & 15;
  __shared__ float rs_s[16];
  int b = b0 + r;
  float p1 = 0.f, p2 = 0.f;
  #pragma unroll
  for (int j = 0; j < 8; j++) {
    int f = l + 16 * j;
    float c = C[b * F_ + f];
    p1 += c * Hm[b * F_ + f];
    p2 += c * cm[f];
  }
  p1 += __shfl_down(p1, 8, 16); p2 += __shfl_down(p2, 8, 16);
  p1 += __shfl_down(p1, 4, 16); p2 += __shfl_down(p2, 4, 16);
  p1 += __shfl_down(p1, 2, 16); p2 += __shfl_down(p2, 2, 16);
  p1 += __shfl_down(p1, 1, 16); p2 += __shfl_down(p2, 1, 16);
  if (l == 0) {
    float E2 = p1 * (1.0f / 4096.0f);
    float mu = p2 * (1.0f / 4096.0f);
    float var = E2 - mu * mu;
    float rs = rsqrtf(var + EPS_);
    rs_s[r] = rs;
    mrs[b] = mu * rs;
  }
  __syncthreads();
  int f = tid & 127, half = tid >> 7;
  ushort_t* xbb = xb + (size_t)blockIdx.x * 4096;
  int k = kbase + f;
  int c = k >> 5, lq = (k >> 3) & 3, j = k & 7;
  #pragma unroll
  for (int i = 0; i < 8; i++) {
    int r2 = half * 8 + i;                      // m = r2
    int lfrag = r2 | (lq << 4);
    xbb[c * 512 + lfrag * 8 + j] = f2us(C[(b0 + r2) * F_ + f] * rs_s[r2]);
  }
}

// ---------------------------------------------------------------------------
// K6 v3 (MFMA): 16 rows x 1024 cy-cols per block, 1024 thr = 16 waves.
// Wave w owns cols [w*64, w*64+64) = colgroups cg = w*4+q, q=0..3.
// Gate tile t = g*64 + cg; 8x mfma_f32_16x16x32_bf16 over K=256 each.
// 16 waves/CU (50% occupancy) to hide B-load latency.
// ---------------------------------------------------------------------------
__global__ __launch_bounds__(1024) void k_fused(
    const ushort_t* __restrict__ xb, const ushort_t* __restrict__ wb,
    const float* __restrict__ mrs_i, const float* __restrict__ mrs_h,
    const void* __restrict__ lniw, const void* __restrict__ lnib,
    const void* __restrict__ lnhw, const void* __restrict__ lnhb,
    const void* __restrict__ lncw, const void* __restrict__ lncb,
    const void* __restrict__ cx, float* __restrict__ out)
{
  __shared__ float wpart[16][16][2];
  __shared__ float mu_s[16], rs_s[16];
  int tid = threadIdx.x;
  int lane = tid & 63, w = tid >> 6;
  int quad = lane >> 4, lcol = lane & 15;
  int b0 = blockIdx.x * 16;
  int fp32 = detect_fp32(lniw);

  // A-fragments for this block's 16 rows (shared by all waves)
  const ushort_t* xblk = xb + (size_t)blockIdx.x * 4096;
  bf8_t af[8];
  #pragma unroll
  for (int c = 0; c < 8; c++)
    af[c] = *(const bf8_t*)(xblk + c * 512 + lane * 8);

  float mi[4], mh[4];
  #pragma unroll
  for (int reg = 0; reg < 4; reg++) {
    mi[reg] = mrs_i[b0 + quad * 4 + reg];
    mh[reg] = mrs_h[b0 + quad * 4 + reg];
  }

  float val[4][4], okeep[4][4];

  #pragma unroll
  for (int q = 0; q < 4; q++) {
    int cg = w * 4 + q;
    int col = cg * 16 + lcol;
    f4_t accg[4];
    #pragma unroll
    for (int g = 0; g < 4; g++) {
      f4_t acc = {0.f, 0.f, 0.f, 0.f};
      int t = g * 64 + cg;
      const ushort_t* wt = wb + (size_t)t * 4096 + lane * 8;
      #pragma unroll
      for (int c = 0; c < 8; c++) {
        bf8_t bf = *(const bf8_t*)(wt + c * 512);
        acc = __builtin_amdgcn_mfma_f32_16x16x32_bf16(af[c], bf, acc, 0, 0, 0);
      }
      accg[g] = acc;
    }
    float liw0 = ldf(lniw, 0 * H_ + col, fp32), lib0 = ldf(lnib, 0 * H_ + col, fp32);
    float lhw0 = ldf(lnhw, 0 * H_ + col, fp32), lhb0 = ldf(lnhb, 0 * H_ + col, fp32);
    float liw1 = ldf(lniw, 1 * H_ + col, fp32), lib1 = ldf(lnib, 1 * H_ + col, fp32);
    float lhw1 = ldf(lnhw, 1 * H_ + col, fp32), lhb1 = ldf(lnhb, 1 * H_ + col, fp32);
    float liw2 = ldf(lniw, 2 * H_ + col, fp32), lib2 = ldf(lnib, 2 * H_ + col, fp32);
    float lhw2 = ldf(lnhw, 2 * H_ + col, fp32), lhb2 = ldf(lnhb, 2 * H_ + col, fp32);
    float liw3 = ldf(lniw, 3 * H_ + col, fp32), lib3 = ldf(lnib, 3 * H_ + col, fp32);
    float lhw3 = ldf(lnhw, 3 * H_ + col, fp32), lhb3 = ldf(lnhb, 3 * H_ + col, fp32);
    #pragma unroll
    for (int reg = 0; reg < 4; reg++) {
      int m = quad * 4 + reg;
      float gi = accg[0][reg] + lib0 + lhb0 - mi[reg] * liw0 - mh[reg] * lhw0;
      float gf = accg[1][reg] + lib1 + lhb1 - mi[reg] * liw1 - mh[reg] * lhw1;
      float gg = accg[2][reg] + lib2 + lhb2 - mi[reg] * liw2 - mh[reg] * lhw2;
      float go = accg[3][reg] + lib3 + lhb3 - mi[reg] * liw3 - mh[reg] * lhw3;
      float iv = sigf(gi), fv = sigf(gf), gv = tanh_f(gg), ov = sigf(go);
      float cxv = ldf(cx, (b0 + m) * H_ + col, fp32);
      val[q][reg] = fv * cxv + iv * gv;
      okeep[q][reg] = ov;
    }
  }

  // cy-LN stats: per-lane partials over q, reduce over 16 lcol lanes, then waves
  float s1[4] = {}, s2[4] = {};
  #pragma unroll
  for (int q = 0; q < 4; q++)
    #pragma unroll
    for (int reg = 0; reg < 4; reg++) {
      s1[reg] += val[q][reg];
      s2[reg] += val[q][reg] * val[q][reg];
    }
  #pragma unroll
  for (int d = 1; d < 16; d <<= 1) {
    #pragma unroll
    for (int reg = 0; reg < 4; reg++) {
      s1[reg] += __shfl_xor(s1[reg], d, 64);
      s2[reg] += __shfl_xor(s2[reg], d, 64);
    }
  }
  if (lcol == 0) {
    #pragma unroll
    for (int reg = 0; reg < 4; reg++) {
      wpart[w][quad * 4 + reg][0] = s1[reg];
      wpart[w][quad * 4 + reg][1] = s2[reg];
    }
  }
  __syncthreads();
  if (tid < 16) {
    float t1 = 0.f, t2 = 0.f;
    #pragma unroll
    for (int ww = 0; ww < 16; ww++) { t1 += wpart[ww][tid][0]; t2 += wpart[ww][tid][1]; }
    float mu = t1 * (1.0f / 1024.0f);
    float var = t2 * (1.0f / 1024.0f) - mu * mu;
    mu_s[tid] = mu;
    rs_s[tid] = rsqrtf(var + EPS_);
  }
  __syncthreads();

  #pragma unroll
  for (int q = 0; q < 4; q++) {
    int col = (w * 4 + q) * 16 + lcol;
    float lw = ldf(lncw, col, fp32), lb = ldf(lncb, col, fp32);
    #pragma unroll
    for (int reg = 0; reg < 4; reg++) {
      int m = quad * 4 + reg;
      float cyv = (val[q][reg] - mu_s[m]) * rs_s[m] * lw + lb;
      float hyv = okeep[q][reg] * tanh_f(cyv);
      out[(b0 + m) * H_ + col] = hyv;
      out[(size_t)B_ * H_ + (b0 + m) * H_ + col] = cyv;
    }
  }
}

// ---------------------------------------------------------------------------
extern "C" void kernel_launch(void* const* d_in, const int* in_sizes, int n_in,
                              void* d_out, int out_size, void* d_ws, size_t ws_size,
                              hipStream_t stream) {
  const void* input_  = d_in[0];
  const void* hx      = d_in[1];
  const void* cx      = d_in[2];
  const void* topic   = d_in[3];
  const void* w_ih_a  = d_in[4];
  const void* w_ih_b  = d_in[5];
  const void* w_ih_c  = d_in[6];
  const void* w_hh_a  = d_in[7];
  const void* w_hh_b  = d_in[8];
  const void* w_hh_c  = d_in[9];
  const void* th_ih_w = d_in[10];
  const void* th_ih_b = d_in[11];
  const void* th_hh_w = d_in[12];
  const void* th_hh_b = d_in[13];
  const void* ln_i_w  = d_in[14];
  const void* ln_i_b  = d_in[15];
  const void* ln_h_w  = d_in[16];
  const void* ln_h_b  = d_in[17];
  const void* ln_c_w  = d_in[18];
  const void* ln_c_b  = d_in[19];

  float* w = (float*)d_ws;
  float* c1    = w;                          // B*F
  float* c2    = c1 + B_ * F_;
  float* h1    = c2 + B_ * F_;
  float* h2    = h1 + B_ * F_;
  float* g_i   = h2 + B_ * F_;               // F*F
  float* g_h   = g_i + F_ * F_;
  float* cm_i  = g_h + F_ * F_;              // F
  float* cm_h  = cm_i + F_;
  float* mrs_i = cm_h + F_;                  // B
  float* mrs_h = mrs_i + B_;
  ushort_t* xb = (ushort_t*)(mrs_h + B_);    // B*256 bf16 (A-frag order)
  ushort_t* wbf = xb + (size_t)B_ * 256;     // 256*4096 bf16 (B-frag order)

  hipMemsetAsync(g_i, 0, (size_t)(2 * F_ * F_ + 2 * F_) * sizeof(float), stream);

  k_prep<<<dim3(256), dim3(256), 0, stream>>>(
      w_ih_a, w_hh_a, ln_i_w, ln_h_w, wbf, cm_i, cm_h);
  k_gemm1<<<dim3(64, 2), dim3(256), 0, stream>>>(
      input_, hx, w_ih_c, w_hh_c, topic,
      th_ih_w, th_hh_w, th_ih_b, th_hh_b, w_ih_b, w_hh_b, ln_i_w, c1, c2);
  k_gram<<<dim3(4, 2, 16), dim3(256), 0, stream>>>(w_ih_a, w_hh_a, ln_i_w, g_i, g_h);
  k_gemm2<<<dim3(128, 2), dim3(256), 0, stream>>>(c1, c2, g_i, g_h, h1, h2);
  k_stats<<<dim3(256, 2), dim3(256), 0, stream>>>(
      c1, c2, h1, h2, cm_i, cm_h, mrs_i, mrs_h, xb);
  k_fused<<<dim3(256), dim3(1024), 0, stream>>>(
      xb, wbf, mrs_i, mrs_h,
      ln_i_w, ln_i_b, ln_h_w, ln_h_b, ln_c_w, ln_c_b, cx, (float*)d_out);
}

// Round 6
// 255.656 us; speedup vs baseline: 1.3980x; 1.3980x over previous
//
#include <hip/hip_runtime.h>

typedef unsigned short ushort_t;
typedef __attribute__((ext_vector_type(8))) short bf8_t;   // 8 x bf16 (4 VGPRs)
typedef __attribute__((ext_vector_type(4))) float f4_t;    // MFMA acc

#define B_   4096
#define IN_  1024
#define H_   1024
#define F_   128
#define G4_  4096
#define EPS_ 1e-5f

#define NG1   512   // gemm1 blocks in stageA
#define NPREP 256   // prep blocks
#define NGRAM 128   // gram blocks

__device__ __forceinline__ float us2f(unsigned short s) {
  union { unsigned int u; float f; } v;
  v.u = ((unsigned int)s) << 16;
  return v.f;
}
__device__ __forceinline__ unsigned short f2us(float f) {  // fp32 -> bf16 RNE
  union { float f; unsigned int u; } v;
  v.f = f;
  unsigned int r = (v.u + 0x7fffu + ((v.u >> 16) & 1u)) >> 16;
  return (unsigned short)r;
}
__device__ __forceinline__ float sigf(float x) { return 1.0f / (1.0f + __expf(-x)); }
__device__ __forceinline__ float tanh_f(float x) { return 1.0f - 2.0f / (1.0f + __expf(2.0f * x)); }

// Runtime input-dtype detection (R1/R2 A/B proved fp32; keep as insurance).
__device__ __forceinline__ int detect_fp32(const void* disc) {
  return ((const unsigned int*)disc)[0] == 0x3F800000u;
}
__device__ __forceinline__ float ldf(const void* p, int i, int fp32) {
  return fp32 ? ((const float*)p)[i] : us2f(((const ushort_t*)p)[i]);
}
__device__ __forceinline__ void ld8(const void* p, int idx, float* o, int fp32) {
  if (fp32) {
    const float4* q = (const float4*)((const float*)p + idx);
    float4 v0 = q[0], v1 = q[1];
    o[0]=v0.x; o[1]=v0.y; o[2]=v0.z; o[3]=v0.w;
    o[4]=v1.x; o[5]=v1.y; o[6]=v1.z; o[7]=v1.w;
  } else {
    uint4 v = *(const uint4*)((const ushort_t*)p + idx);
    const ushort_t* pv = (const ushort_t*)&v;
    #pragma unroll
    for (int i = 0; i < 8; i++) o[i] = us2f(pv[i]);
  }
}
// fast fp32x8 -> bf16x8: round-half-up + v_perm_b32 byte pack (1.5 op/elem)
__device__ __forceinline__ bf8_t cvt8p(const float* f) {
  union { bf8_t v; unsigned int u[4]; } r;
  const unsigned int* ui = (const unsigned int*)f;
  #pragma unroll
  for (int i = 0; i < 4; i++) {
    unsigned int lo = ui[2 * i] + 0x8000u;
    unsigned int hi = ui[2 * i + 1] + 0x8000u;
    r.u[i] = __builtin_amdgcn_perm(hi, lo, 0x07060302u);
  }
  return r.v;
}

// ---------------------------------------------------------------------------
// stageA: three independent jobs fused into one launch for co-residency.
//  bid <  NG1          : gemm1 (MFMA)  C[b][f] = (X@Wc^T)*scale
//  bid <  NG1+NPREP    : prep (wb B-frags + colsum partials)
//  else                : gram  G = A^T A (split-K, atomics)
// ---------------------------------------------------------------------------
__global__ __launch_bounds__(256) void k_stageA(
    const void* __restrict__ X0, const void* __restrict__ X1,
    const void* __restrict__ Wc0, const void* __restrict__ Wc1,
    const void* __restrict__ topic,
    const void* __restrict__ thw0, const void* __restrict__ thw1,
    const void* __restrict__ thb0, const void* __restrict__ thb1,
    const void* __restrict__ wsb0, const void* __restrict__ wsb1,
    const void* __restrict__ Ai, const void* __restrict__ Ah,
    const void* __restrict__ lnwi, const void* __restrict__ lnwh,
    ushort_t* __restrict__ wb,
    float* __restrict__ cm_i, float* __restrict__ cm_h,
    float* __restrict__ g_i, float* __restrict__ g_h,
    float* __restrict__ C0, float* __restrict__ C1)
{
  __shared__ float smem[32 * 128];   // used by gram branch only
  int bid = blockIdx.x, tid = threadIdx.x;
  int fp32 = detect_fp32(lnwi);

  if (bid < NG1) {
    // ---------------- gemm1: 16 rows x 128 cols per block, 4 waves ----------
    int rb = bid >> 1, mat = bid & 1;
    const void* X   = mat ? X1 : X0;
    const void* W   = mat ? Wc1 : Wc0;
    const void* thw = mat ? thw1 : thw0;
    const void* thb = mat ? thb1 : thb0;
    const void* wbp = mat ? wsb1 : wsb0;
    float* C = mat ? C1 : C0;
    int lane = tid & 63, w = tid >> 6;
    int quad = lane >> 4, lcol = lane & 15;
    int brow0 = rb * 16;

    f4_t acc[2];
    acc[0] = (f4_t){0.f, 0.f, 0.f, 0.f};
    acc[1] = (f4_t){0.f, 0.f, 0.f, 0.f};

    #pragma unroll 4
    for (int kc = 0; kc < 32; kc++) {
      int kb = kc * 32 + quad * 8;
      float a[8];
      ld8(X, (brow0 + lcol) * IN_ + kb, a, fp32);
      bf8_t af = cvt8p(a);
      #pragma unroll
      for (int t = 0; t < 2; t++) {
        float bt[8];
        ld8(W, ((w * 2 + t) * 16 + lcol) * IN_ + kb, bt, fp32);
        acc[t] = __builtin_amdgcn_mfma_f32_16x16x32_bf16(af, cvt8p(bt), acc[t], 0, 0, 0);
      }
    }

    // epilogue: scale(b,f)
    float thwf[3][3], thbf[3];
    #pragma unroll
    for (int t = 0; t < 3; t++) {
      thbf[t] = ldf(thb, t, fp32);
      #pragma unroll
      for (int t2 = 0; t2 < 3; t2++) thwf[t][t2] = ldf(thw, t * 3 + t2, fp32);
    }
    float tmpv[4][3];
    #pragma unroll
    for (int reg = 0; reg < 4; reg++) {
      int b = brow0 + quad * 4 + reg;
      float tp0 = ldf(topic, b * 3 + 0, fp32);
      float tp1 = ldf(topic, b * 3 + 1, fp32);
      float tp2 = ldf(topic, b * 3 + 2, fp32);
      #pragma unroll
      for (int t = 0; t < 3; t++)
        tmpv[reg][t] = thbf[t] + tp0 * thwf[t][0] + tp1 * thwf[t][1] + tp2 * thwf[t][2];
    }
    #pragma unroll
    for (int t = 0; t < 2; t++) {
      int f = (w * 2 + t) * 16 + lcol;
      float wv0 = ldf(wbp, f * 3 + 0, fp32);
      float wv1 = ldf(wbp, f * 3 + 1, fp32);
      float wv2 = ldf(wbp, f * 3 + 2, fp32);
      #pragma unroll
      for (int reg = 0; reg < 4; reg++) {
        float sc = tmpv[reg][0] * wv0 + tmpv[reg][1] * wv1 + tmpv[reg][2] * wv2;
        C[(brow0 + quad * 4 + reg) * F_ + f] = acc[t][reg] * sc;
      }
    }
  } else if (bid < NG1 + NPREP) {
    // ---------------- prep: wb B-frags + colsum partials ---------------------
    int t = bid - NG1;
    #pragma unroll
    for (int i = 0; i < 16; i++) {
      int e = i * 256 + tid;
      int c = e >> 9, l = (e >> 3) & 63, j = e & 7;
      int k = c * 32 + ((l >> 4) << 3) + j;
      int n = t * 16 + (l & 15);
      float v;
      if (k < 128) v = ldf(Ai, n * F_ + k, fp32) * ldf(lnwi, n, fp32);
      else         v = ldf(Ah, n * F_ + (k - 128), fp32) * ldf(lnwh, n, fp32);
      wb[(size_t)t * 4096 + e] = f2us(v);
    }
    const void* A = (tid < 128) ? Ai : Ah;
    float* cm = (tid < 128) ? cm_i : cm_h;
    int f = tid & 127;
    float s = 0.f;
    #pragma unroll
    for (int i = 0; i < 16; i++) s += ldf(A, (t * 16 + i) * F_ + f, fp32);
    atomicAdd(&cm[f], s);
  } else {
    // ---------------- gram: G = A^T A, split-K -------------------------------
    int g = bid - (NG1 + NPREP);
    int fblk = g & 3, mat = (g >> 2) & 1, z = g >> 3;
    const void* A = mat ? Ah : Ai;
    float* G = mat ? g_h : g_i;
    float (*As)[128] = (float(*)[128])smem;
    int f1_0 = fblk * 32;
    int tf2 = tid & 31, tf1 = tid >> 5;
    float acc[4][4] = {};
    int nbase = z * 256;
    for (int n0 = nbase; n0 < nbase + 256; n0 += 32) {
      #pragma unroll
      for (int j = 0; j < 2; j++) {
        int idx = tid + 256 * j;
        int nn = idx >> 4, f8 = (idx & 15) * 8;
        float t[8];
        ld8(A, (n0 + nn) * F_ + f8, t, fp32);
        #pragma unroll
        for (int i = 0; i < 8; i++) As[nn][f8 + i] = t[i];
      }
      __syncthreads();
      #pragma unroll 4
      for (int nn = 0; nn < 32; nn++) {
        float4 a1 = *(const float4*)&As[nn][f1_0 + 4 * tf1];
        float4 a2 = *(const float4*)&As[nn][4 * tf2];
        const float* x1 = (const float*)&a1;
        const float* x2 = (const float*)&a2;
        #pragma unroll
        for (int i = 0; i < 4; i++)
          #pragma unroll
          for (int j = 0; j < 4; j++) acc[i][j] += x1[i] * x2[j];
      }
      __syncthreads();
    }
    #pragma unroll
    for (int i = 0; i < 4; i++)
      #pragma unroll
      for (int j = 0; j < 4; j++)
        atomicAdd(&G[(f1_0 + 4 * tf1 + i) * F_ + 4 * tf2 + j], acc[i][j]);
  }
}

// ---------------------------------------------------------------------------
// stats2: per-row LN stats via quadratic form p1 = C_b^T G C_b (MFMA, G
// symmetric -> row-major loads are B-frags), p2 = C_b . cm; write xb A-frags.
// Replaces k_gemm2 + k_stats. grid 512 (rb 256 x mat 2), 256 thr / 4 waves.
// ---------------------------------------------------------------------------
__global__ __launch_bounds__(256) void k_stats2(
    const float* __restrict__ C0, const float* __restrict__ C1,
    const float* __restrict__ g_i, const float* __restrict__ g_h,
    const float* __restrict__ cm_i, const float* __restrict__ cm_h,
    float* __restrict__ mrs_i, float* __restrict__ mrs_h,
    ushort_t* __restrict__ xb)
{
  int bid = blockIdx.x;
  int rb = bid >> 1, mat = bid & 1;
  const float* C  = mat ? C1 : C0;
  const float* G  = mat ? g_h : g_i;
  const float* cm = mat ? cm_h : cm_i;
  float* mrs = mat ? mrs_h : mrs_i;
  int kbase = mat ? 128 : 0;

  int tid = threadIdx.x;
  int lane = tid & 63, w = tid >> 6;
  int quad = lane >> 4, lcol = lane & 15;
  int b0 = rb * 16;

  __shared__ float p1part[4][16];
  __shared__ float p2s[16];
  __shared__ float rs_s[16];

  // A-frags of C (m=lcol, k=quad*8+j per 32-chunk) + p2 partial (wave 0)
  bf8_t af[4];
  float p2p = 0.f;
  #pragma unroll
  for (int kc = 0; kc < 4; kc++) {
    int kb = kc * 32 + quad * 8;
    const float4* q = (const float4*)(C + (b0 + lcol) * F_ + kb);
    float4 v0 = q[0], v1 = q[1];
    float a[8] = {v0.x, v0.y, v0.z, v0.w, v1.x, v1.y, v1.z, v1.w};
    af[kc] = cvt8p(a);
    if (w == 0) {
      #pragma unroll
      for (int j = 0; j < 8; j++) p2p += a[j] * cm[kb + j];
    }
  }

  // H tile cols (w*2+t)*16+lcol via MFMA; p1 partial = C .* H
  float p1p[4] = {0.f, 0.f, 0.f, 0.f};
  #pragma unroll
  for (int t = 0; t < 2; t++) {
    int colf = (w * 2 + t) * 16 + lcol;
    f4_t acc = {0.f, 0.f, 0.f, 0.f};
    #pragma unroll
    for (int kc = 0; kc < 4; kc++) {
      const float4* qg = (const float4*)(G + colf * F_ + kc * 32 + quad * 8);
      float4 w0 = qg[0], w1 = qg[1];
      float bt[8] = {w0.x, w0.y, w0.z, w0.w, w1.x, w1.y, w1.z, w1.w};
      acc = __builtin_amdgcn_mfma_f32_16x16x32_bf16(af[kc], cvt8p(bt), acc, 0, 0, 0);
    }
    #pragma unroll
    for (int reg = 0; reg < 4; reg++)
      p1p[reg] += acc[reg] * C[(b0 + quad * 4 + reg) * F_ + colf];
  }
  // reduce p1 over the 16 lcol lanes (within quad)
  #pragma unroll
  for (int d = 1; d < 16; d <<= 1)
    #pragma unroll
    for (int reg = 0; reg < 4; reg++)
      p1p[reg] += __shfl_xor(p1p[reg], d, 64);
  if (lcol == 0) {
    #pragma unroll
    for (int reg = 0; reg < 4; reg++)
      p1part[w][quad * 4 + reg] = p1p[reg];
  }
  // reduce p2 over quads (wave 0 only)
  if (w == 0) {
    p2p += __shfl_xor(p2p, 16, 64);
    p2p += __shfl_xor(p2p, 32, 64);
    if (quad == 0) p2s[lcol] = p2p;
  }
  __syncthreads();
  if (tid < 16) {
    float p1 = p1part[0][tid] + p1part[1][tid] + p1part[2][tid] + p1part[3][tid];
    float E2 = p1 * (1.0f / 4096.0f);
    float mu = p2s[tid] * (1.0f / 4096.0f);
    float var = E2 - mu * mu;
    float rs = rsqrtf(var + EPS_);
    rs_s[tid] = rs;
    mrs[b0 + tid] = mu * rs;
  }
  __syncthreads();
  // xb write (rs-scaled C in bf16 A-frag order)
  int f = tid & 127, half = tid >> 7;
  ushort_t* xbb = xb + (size_t)rb * 4096;
  int k = kbase + f;
  int c = k >> 5, lq = (k >> 3) & 3, j = k & 7;
  #pragma unroll
  for (int i = 0; i < 8; i++) {
    int r2 = half * 8 + i;
    int lfrag = r2 | (lq << 4);
    xbb[c * 512 + lfrag * 8 + j] = f2us(C[(b0 + r2) * F_ + f] * rs_s[r2]);
  }
}

// ---------------------------------------------------------------------------
// K6 v3 (MFMA): 16 rows x 1024 cy-cols per block, 1024 thr = 16 waves.
// (unchanged from R5)
// ---------------------------------------------------------------------------
__global__ __launch_bounds__(1024) void k_fused(
    const ushort_t* __restrict__ xb, const ushort_t* __restrict__ wb,
    const float* __restrict__ mrs_i, const float* __restrict__ mrs_h,
    const void* __restrict__ lniw, const void* __restrict__ lnib,
    const void* __restrict__ lnhw, const void* __restrict__ lnhb,
    const void* __restrict__ lncw, const void* __restrict__ lncb,
    const void* __restrict__ cx, float* __restrict__ out)
{
  __shared__ float wpart[16][16][2];
  __shared__ float mu_s[16], rs_s[16];
  int tid = threadIdx.x;
  int lane = tid & 63, w = tid >> 6;
  int quad = lane >> 4, lcol = lane & 15;
  int b0 = blockIdx.x * 16;
  int fp32 = detect_fp32(lniw);

  const ushort_t* xblk = xb + (size_t)blockIdx.x * 4096;
  bf8_t af[8];
  #pragma unroll
  for (int c = 0; c < 8; c++)
    af[c] = *(const bf8_t*)(xblk + c * 512 + lane * 8);

  float mi[4], mh[4];
  #pragma unroll
  for (int reg = 0; reg < 4; reg++) {
    mi[reg] = mrs_i[b0 + quad * 4 + reg];
    mh[reg] = mrs_h[b0 + quad * 4 + reg];
  }

  float val[4][4], okeep[4][4];

  #pragma unroll
  for (int q = 0; q < 4; q++) {
    int cg = w * 4 + q;
    int col = cg * 16 + lcol;
    f4_t accg[4];
    #pragma unroll
    for (int g = 0; g < 4; g++) {
      f4_t acc = {0.f, 0.f, 0.f, 0.f};
      int t = g * 64 + cg;
      const ushort_t* wt = wb + (size_t)t * 4096 + lane * 8;
      #pragma unroll
      for (int c = 0; c < 8; c++) {
        bf8_t bf = *(const bf8_t*)(wt + c * 512);
        acc = __builtin_amdgcn_mfma_f32_16x16x32_bf16(af[c], bf, acc, 0, 0, 0);
      }
      accg[g] = acc;
    }
    float liw0 = ldf(lniw, 0 * H_ + col, fp32), lib0 = ldf(lnib, 0 * H_ + col, fp32);
    float lhw0 = ldf(lnhw, 0 * H_ + col, fp32), lhb0 = ldf(lnhb, 0 * H_ + col, fp32);
    float liw1 = ldf(lniw, 1 * H_ + col, fp32), lib1 = ldf(lnib, 1 * H_ + col, fp32);
    float lhw1 = ldf(lnhw, 1 * H_ + col, fp32), lhb1 = ldf(lnhb, 1 * H_ + col, fp32);
    float liw2 = ldf(lniw, 2 * H_ + col, fp32), lib2 = ldf(lnib, 2 * H_ + col, fp32);
    float lhw2 = ldf(lnhw, 2 * H_ + col, fp32), lhb2 = ldf(lnhb, 2 * H_ + col, fp32);
    float liw3 = ldf(lniw, 3 * H_ + col, fp32), lib3 = ldf(lnib, 3 * H_ + col, fp32);
    float lhw3 = ldf(lnhw, 3 * H_ + col, fp32), lhb3 = ldf(lnhb, 3 * H_ + col, fp32);
    #pragma unroll
    for (int reg = 0; reg < 4; reg++) {
      int m = quad * 4 + reg;
      float gi = accg[0][reg] + lib0 + lhb0 - mi[reg] * liw0 - mh[reg] * lhw0;
      float gf = accg[1][reg] + lib1 + lhb1 - mi[reg] * liw1 - mh[reg] * lhw1;
      float gg = accg[2][reg] + lib2 + lhb2 - mi[reg] * liw2 - mh[reg] * lhw2;
      float go = accg[3][reg] + lib3 + lhb3 - mi[reg] * liw3 - mh[reg] * lhw3;
      float iv = sigf(gi), fv = sigf(gf), gv = tanh_f(gg), ov = sigf(go);
      float cxv = ldf(cx, (b0 + m) * H_ + col, fp32);
      val[q][reg] = fv * cxv + iv * gv;
      okeep[q][reg] = ov;
    }
  }

  float s1[4] = {}, s2[4] = {};
  #pragma unroll
  for (int q = 0; q < 4; q++)
    #pragma unroll
    for (int reg = 0; reg < 4; reg++) {
      s1[reg] += val[q][reg];
      s2[reg] += val[q][reg] * val[q][reg];
    }
  #pragma unroll
  for (int d = 1; d < 16; d <<= 1) {
    #pragma unroll
    for (int reg = 0; reg < 4; reg++) {
      s1[reg] += __shfl_xor(s1[reg], d, 64);
      s2[reg] += __shfl_xor(s2[reg], d, 64);
    }
  }
  if (lcol == 0) {
    #pragma unroll
    for (int reg = 0; reg < 4; reg++) {
      wpart[w][quad * 4 + reg][0] = s1[reg];
      wpart[w][quad * 4 + reg][1] = s2[reg];
    }
  }
  __syncthreads();
  if (tid < 16) {
    float t1 = 0.f, t2 = 0.f;
    #pragma unroll
    for (int ww = 0; ww < 16; ww++) { t1 += wpart[ww][tid][0]; t2 += wpart[ww][tid][1]; }
    float mu = t1 * (1.0f / 1024.0f);
    float var = t2 * (1.0f / 1024.0f) - mu * mu;
    mu_s[tid] = mu;
    rs_s[tid] = rsqrtf(var + EPS_);
  }
  __syncthreads();

  #pragma unroll
  for (int q = 0; q < 4; q++) {
    int col = (w * 4 + q) * 16 + lcol;
    float lw = ldf(lncw, col, fp32), lb = ldf(lncb, col, fp32);
    #pragma unroll
    for (int reg = 0; reg < 4; reg++) {
      int m = quad * 4 + reg;
      float cyv = (val[q][reg] - mu_s[m]) * rs_s[m] * lw + lb;
      float hyv = okeep[q][reg] * tanh_f(cyv);
      out[(b0 + m) * H_ + col] = hyv;
      out[(size_t)B_ * H_ + (b0 + m) * H_ + col] = cyv;
    }
  }
}

// ---------------------------------------------------------------------------
extern "C" void kernel_launch(void* const* d_in, const int* in_sizes, int n_in,
                              void* d_out, int out_size, void* d_ws, size_t ws_size,
                              hipStream_t stream) {
  const void* input_  = d_in[0];
  const void* hx      = d_in[1];
  const void* cx      = d_in[2];
  const void* topic   = d_in[3];
  const void* w_ih_a  = d_in[4];
  const void* w_ih_b  = d_in[5];
  const void* w_ih_c  = d_in[6];
  const void* w_hh_a  = d_in[7];
  const void* w_hh_b  = d_in[8];
  const void* w_hh_c  = d_in[9];
  const void* th_ih_w = d_in[10];
  const void* th_ih_b = d_in[11];
  const void* th_hh_w = d_in[12];
  const void* th_hh_b = d_in[13];
  const void* ln_i_w  = d_in[14];
  const void* ln_i_b  = d_in[15];
  const void* ln_h_w  = d_in[16];
  const void* ln_h_b  = d_in[17];
  const void* ln_c_w  = d_in[18];
  const void* ln_c_b  = d_in[19];

  float* w = (float*)d_ws;
  float* c1    = w;                          // B*F
  float* c2    = c1 + B_ * F_;
  float* g_i   = c2 + B_ * F_;               // F*F
  float* g_h   = g_i + F_ * F_;
  float* cm_i  = g_h + F_ * F_;              // F
  float* cm_h  = cm_i + F_;
  float* mrs_i = cm_h + F_;                  // B
  float* mrs_h = mrs_i + B_;
  ushort_t* xb = (ushort_t*)(mrs_h + B_);    // B*256 bf16 (A-frag order)
  ushort_t* wbf = xb + (size_t)B_ * 256;     // 256*4096 bf16 (B-frag order)

  hipMemsetAsync(g_i, 0, (size_t)(2 * F_ * F_ + 2 * F_) * sizeof(float), stream);

  k_stageA<<<dim3(NG1 + NPREP + NGRAM), dim3(256), 0, stream>>>(
      input_, hx, w_ih_c, w_hh_c, topic,
      th_ih_w, th_hh_w, th_ih_b, th_hh_b, w_ih_b, w_hh_b,
      w_ih_a, w_hh_a, ln_i_w, ln_h_w,
      wbf, cm_i, cm_h, g_i, g_h, c1, c2);
  k_stats2<<<dim3(512), dim3(256), 0, stream>>>(
      c1, c2, g_i, g_h, cm_i, cm_h, mrs_i, mrs_h, xb);
  k_fused<<<dim3(256), dim3(1024), 0, stream>>>(
      xb, wbf, mrs_i, mrs_h,
      ln_i_w, ln_i_b, ln_h_w, ln_h_b, ln_c_w, ln_c_b, cx, (float*)d_out);
}

// Round 7
// 252.629 us; speedup vs baseline: 1.4147x; 1.0120x over previous
//
#include <hip/hip_runtime.h>

typedef unsigned short ushort_t;
typedef __attribute__((ext_vector_type(8))) short bf8_t;   // 8 x bf16 (4 VGPRs)
typedef __attribute__((ext_vector_type(4))) float f4_t;    // MFMA acc

#define B_   4096
#define IN_  1024
#define H_   1024
#define F_   128
#define G4_  4096
#define EPS_ 1e-5f

#define NG1   512   // gemm1 blocks in stageA
#define NPREP 256   // prep blocks
#define NGRAM 128   // gram blocks

__device__ __forceinline__ float us2f(unsigned short s) {
  union { unsigned int u; float f; } v;
  v.u = ((unsigned int)s) << 16;
  return v.f;
}
__device__ __forceinline__ unsigned short f2us(float f) {  // fp32 -> bf16 RNE
  union { float f; unsigned int u; } v;
  v.f = f;
  unsigned int r = (v.u + 0x7fffu + ((v.u >> 16) & 1u)) >> 16;
  return (unsigned short)r;
}
__device__ __forceinline__ float sigf(float x) { return 1.0f / (1.0f + __expf(-x)); }
__device__ __forceinline__ float tanh_f(float x) { return 1.0f - 2.0f / (1.0f + __expf(2.0f * x)); }

// Runtime input-dtype detection (R1/R2 A/B proved fp32; keep as insurance).
__device__ __forceinline__ int detect_fp32(const void* disc) {
  return ((const unsigned int*)disc)[0] == 0x3F800000u;
}
__device__ __forceinline__ float ldf(const void* p, int i, int fp32) {
  return fp32 ? ((const float*)p)[i] : us2f(((const ushort_t*)p)[i]);
}
__device__ __forceinline__ void ld8(const void* p, int idx, float* o, int fp32) {
  if (fp32) {
    const float4* q = (const float4*)((const float*)p + idx);
    float4 v0 = q[0], v1 = q[1];
    o[0]=v0.x; o[1]=v0.y; o[2]=v0.z; o[3]=v0.w;
    o[4]=v1.x; o[5]=v1.y; o[6]=v1.z; o[7]=v1.w;
  } else {
    uint4 v = *(const uint4*)((const ushort_t*)p + idx);
    const ushort_t* pv = (const ushort_t*)&v;
    #pragma unroll
    for (int i = 0; i < 8; i++) o[i] = us2f(pv[i]);
  }
}
// fast fp32x8 -> bf16x8: round-half-up + v_perm_b32 byte pack (1.5 op/elem)
__device__ __forceinline__ bf8_t cvt8p(const float* f) {
  union { bf8_t v; unsigned int u[4]; } r;
  const unsigned int* ui = (const unsigned int*)f;
  #pragma unroll
  for (int i = 0; i < 4; i++) {
    unsigned int lo = ui[2 * i] + 0x8000u;
    unsigned int hi = ui[2 * i + 1] + 0x8000u;
    r.u[i] = __builtin_amdgcn_perm(hi, lo, 0x07060302u);
  }
  return r.v;
}

// ---------------------------------------------------------------------------
// stageA: three independent jobs fused into one launch for co-residency.
//  (unchanged from R6)
// ---------------------------------------------------------------------------
__global__ __launch_bounds__(256) void k_stageA(
    const void* __restrict__ X0, const void* __restrict__ X1,
    const void* __restrict__ Wc0, const void* __restrict__ Wc1,
    const void* __restrict__ topic,
    const void* __restrict__ thw0, const void* __restrict__ thw1,
    const void* __restrict__ thb0, const void* __restrict__ thb1,
    const void* __restrict__ wsb0, const void* __restrict__ wsb1,
    const void* __restrict__ Ai, const void* __restrict__ Ah,
    const void* __restrict__ lnwi, const void* __restrict__ lnwh,
    ushort_t* __restrict__ wb,
    float* __restrict__ cm_i, float* __restrict__ cm_h,
    float* __restrict__ g_i, float* __restrict__ g_h,
    float* __restrict__ C0, float* __restrict__ C1)
{
  __shared__ float smem[32 * 128];   // used by gram branch only
  int bid = blockIdx.x, tid = threadIdx.x;
  int fp32 = detect_fp32(lnwi);

  if (bid < NG1) {
    int rb = bid >> 1, mat = bid & 1;
    const void* X   = mat ? X1 : X0;
    const void* W   = mat ? Wc1 : Wc0;
    const void* thw = mat ? thw1 : thw0;
    const void* thb = mat ? thb1 : thb0;
    const void* wbp = mat ? wsb1 : wsb0;
    float* C = mat ? C1 : C0;
    int lane = tid & 63, w = tid >> 6;
    int quad = lane >> 4, lcol = lane & 15;
    int brow0 = rb * 16;

    f4_t acc[2];
    acc[0] = (f4_t){0.f, 0.f, 0.f, 0.f};
    acc[1] = (f4_t){0.f, 0.f, 0.f, 0.f};

    #pragma unroll 4
    for (int kc = 0; kc < 32; kc++) {
      int kb = kc * 32 + quad * 8;
      float a[8];
      ld8(X, (brow0 + lcol) * IN_ + kb, a, fp32);
      bf8_t af = cvt8p(a);
      #pragma unroll
      for (int t = 0; t < 2; t++) {
        float bt[8];
        ld8(W, ((w * 2 + t) * 16 + lcol) * IN_ + kb, bt, fp32);
        acc[t] = __builtin_amdgcn_mfma_f32_16x16x32_bf16(af, cvt8p(bt), acc[t], 0, 0, 0);
      }
    }

    float thwf[3][3], thbf[3];
    #pragma unroll
    for (int t = 0; t < 3; t++) {
      thbf[t] = ldf(thb, t, fp32);
      #pragma unroll
      for (int t2 = 0; t2 < 3; t2++) thwf[t][t2] = ldf(thw, t * 3 + t2, fp32);
    }
    float tmpv[4][3];
    #pragma unroll
    for (int reg = 0; reg < 4; reg++) {
      int b = brow0 + quad * 4 + reg;
      float tp0 = ldf(topic, b * 3 + 0, fp32);
      float tp1 = ldf(topic, b * 3 + 1, fp32);
      float tp2 = ldf(topic, b * 3 + 2, fp32);
      #pragma unroll
      for (int t = 0; t < 3; t++)
        tmpv[reg][t] = thbf[t] + tp0 * thwf[t][0] + tp1 * thwf[t][1] + tp2 * thwf[t][2];
    }
    #pragma unroll
    for (int t = 0; t < 2; t++) {
      int f = (w * 2 + t) * 16 + lcol;
      float wv0 = ldf(wbp, f * 3 + 0, fp32);
      float wv1 = ldf(wbp, f * 3 + 1, fp32);
      float wv2 = ldf(wbp, f * 3 + 2, fp32);
      #pragma unroll
      for (int reg = 0; reg < 4; reg++) {
        float sc = tmpv[reg][0] * wv0 + tmpv[reg][1] * wv1 + tmpv[reg][2] * wv2;
        C[(brow0 + quad * 4 + reg) * F_ + f] = acc[t][reg] * sc;
      }
    }
  } else if (bid < NG1 + NPREP) {
    int t = bid - NG1;
    #pragma unroll
    for (int i = 0; i < 16; i++) {
      int e = i * 256 + tid;
      int c = e >> 9, l = (e >> 3) & 63, j = e & 7;
      int k = c * 32 + ((l >> 4) << 3) + j;
      int n = t * 16 + (l & 15);
      float v;
      if (k < 128) v = ldf(Ai, n * F_ + k, fp32) * ldf(lnwi, n, fp32);
      else         v = ldf(Ah, n * F_ + (k - 128), fp32) * ldf(lnwh, n, fp32);
      wb[(size_t)t * 4096 + e] = f2us(v);
    }
    const void* A = (tid < 128) ? Ai : Ah;
    float* cm = (tid < 128) ? cm_i : cm_h;
    int f = tid & 127;
    float s = 0.f;
    #pragma unroll
    for (int i = 0; i < 16; i++) s += ldf(A, (t * 16 + i) * F_ + f, fp32);
    atomicAdd(&cm[f], s);
  } else {
    int g = bid - (NG1 + NPREP);
    int fblk = g & 3, mat = (g >> 2) & 1, z = g >> 3;
    const void* A = mat ? Ah : Ai;
    float* G = mat ? g_h : g_i;
    float (*As)[128] = (float(*)[128])smem;
    int f1_0 = fblk * 32;
    int tf2 = tid & 31, tf1 = tid >> 5;
    float acc[4][4] = {};
    int nbase = z * 256;
    for (int n0 = nbase; n0 < nbase + 256; n0 += 32) {
      #pragma unroll
      for (int j = 0; j < 2; j++) {
        int idx = tid + 256 * j;
        int nn = idx >> 4, f8 = (idx & 15) * 8;
        float t[8];
        ld8(A, (n0 + nn) * F_ + f8, t, fp32);
        #pragma unroll
        for (int i = 0; i < 8; i++) As[nn][f8 + i] = t[i];
      }
      __syncthreads();
      #pragma unroll 4
      for (int nn = 0; nn < 32; nn++) {
        float4 a1 = *(const float4*)&As[nn][f1_0 + 4 * tf1];
        float4 a2 = *(const float4*)&As[nn][4 * tf2];
        const float* x1 = (const float*)&a1;
        const float* x2 = (const float*)&a2;
        #pragma unroll
        for (int i = 0; i < 4; i++)
          #pragma unroll
          for (int j = 0; j < 4; j++) acc[i][j] += x1[i] * x2[j];
      }
      __syncthreads();
    }
    #pragma unroll
    for (int i = 0; i < 4; i++)
      #pragma unroll
      for (int j = 0; j < 4; j++)
        atomicAdd(&G[(f1_0 + 4 * tf1 + i) * F_ + 4 * tf2 + j], acc[i][j]);
  }
}

// ---------------------------------------------------------------------------
// stats2: per-row LN stats via quadratic form (unchanged from R6)
// ---------------------------------------------------------------------------
__global__ __launch_bounds__(256) void k_stats2(
    const float* __restrict__ C0, const float* __restrict__ C1,
    const float* __restrict__ g_i, const float* __restrict__ g_h,
    const float* __restrict__ cm_i, const float* __restrict__ cm_h,
    float* __restrict__ mrs_i, float* __restrict__ mrs_h,
    ushort_t* __restrict__ xb)
{
  int bid = blockIdx.x;
  int rb = bid >> 1, mat = bid & 1;
  const float* C  = mat ? C1 : C0;
  const float* G  = mat ? g_h : g_i;
  const float* cm = mat ? cm_h : cm_i;
  float* mrs = mat ? mrs_h : mrs_i;
  int kbase = mat ? 128 : 0;

  int tid = threadIdx.x;
  int lane = tid & 63, w = tid >> 6;
  int quad = lane >> 4, lcol = lane & 15;
  int b0 = rb * 16;

  __shared__ float p1part[4][16];
  __shared__ float p2s[16];
  __shared__ float rs_s[16];

  bf8_t af[4];
  float p2p = 0.f;
  #pragma unroll
  for (int kc = 0; kc < 4; kc++) {
    int kb = kc * 32 + quad * 8;
    const float4* q = (const float4*)(C + (b0 + lcol) * F_ + kb);
    float4 v0 = q[0], v1 = q[1];
    float a[8] = {v0.x, v0.y, v0.z, v0.w, v1.x, v1.y, v1.z, v1.w};
    af[kc] = cvt8p(a);
    if (w == 0) {
      #pragma unroll
      for (int j = 0; j < 8; j++) p2p += a[j] * cm[kb + j];
    }
  }

  float p1p[4] = {0.f, 0.f, 0.f, 0.f};
  #pragma unroll
  for (int t = 0; t < 2; t++) {
    int colf = (w * 2 + t) * 16 + lcol;
    f4_t acc = {0.f, 0.f, 0.f, 0.f};
    #pragma unroll
    for (int kc = 0; kc < 4; kc++) {
      const float4* qg = (const float4*)(G + colf * F_ + kc * 32 + quad * 8);
      float4 w0 = qg[0], w1 = qg[1];
      float bt[8] = {w0.x, w0.y, w0.z, w0.w, w1.x, w1.y, w1.z, w1.w};
      acc = __builtin_amdgcn_mfma_f32_16x16x32_bf16(af[kc], cvt8p(bt), acc, 0, 0, 0);
    }
    #pragma unroll
    for (int reg = 0; reg < 4; reg++)
      p1p[reg] += acc[reg] * C[(b0 + quad * 4 + reg) * F_ + colf];
  }
  #pragma unroll
  for (int d = 1; d < 16; d <<= 1)
    #pragma unroll
    for (int reg = 0; reg < 4; reg++)
      p1p[reg] += __shfl_xor(p1p[reg], d, 64);
  if (lcol == 0) {
    #pragma unroll
    for (int reg = 0; reg < 4; reg++)
      p1part[w][quad * 4 + reg] = p1p[reg];
  }
  if (w == 0) {
    p2p += __shfl_xor(p2p, 16, 64);
    p2p += __shfl_xor(p2p, 32, 64);
    if (quad == 0) p2s[lcol] = p2p;
  }
  __syncthreads();
  if (tid < 16) {
    float p1 = p1part[0][tid] + p1part[1][tid] + p1part[2][tid] + p1part[3][tid];
    float E2 = p1 * (1.0f / 4096.0f);
    float mu = p2s[tid] * (1.0f / 4096.0f);
    float var = E2 - mu * mu;
    float rs = rsqrtf(var + EPS_);
    rs_s[tid] = rs;
    mrs[b0 + tid] = mu * rs;
  }
  __syncthreads();
  int f = tid & 127, half = tid >> 7;
  ushort_t* xbb = xb + (size_t)rb * 4096;
  int k = kbase + f;
  int c = k >> 5, lq = (k >> 3) & 3, j = k & 7;
  #pragma unroll
  for (int i = 0; i < 8; i++) {
    int r2 = half * 8 + i;
    int lfrag = r2 | (lq << 4);
    xbb[c * 512 + lfrag * 8 + j] = f2us(C[(b0 + r2) * F_ + f] * rs_s[r2]);
  }
}

// ---------------------------------------------------------------------------
// K6 v4 (MFMA + coalesced I/O): 16 rows x 1024 cols per block, 16 waves.
// cx staged into LDS (coalesced); cy/hy staged to LDS in MFMA layout then
// stored as contiguous float4 wave-segments (kills 3x write amplification
// seen in R6: WRITE_SIZE 97 MB vs 32 MB ideal).
// buf row stride 1028: quad rows land 16 banks apart -> worst 2-way (free).
// ---------------------------------------------------------------------------
__global__ __launch_bounds__(1024) void k_fused(
    const ushort_t* __restrict__ xb, const ushort_t* __restrict__ wb,
    const float* __restrict__ mrs_i, const float* __restrict__ mrs_h,
    const void* __restrict__ lniw, const void* __restrict__ lnib,
    const void* __restrict__ lnhw, const void* __restrict__ lnhb,
    const void* __restrict__ lncw, const void* __restrict__ lncb,
    const void* __restrict__ cx, float* __restrict__ out)
{
  __shared__ float buf[16][1028];
  __shared__ float wpart[16][16][2];
  __shared__ float mu_s[16], rs_s[16];
  int tid = threadIdx.x;
  int lane = tid & 63, w = tid >> 6;
  int quad = lane >> 4, lcol = lane & 15;
  int b0 = blockIdx.x * 16;
  int fp32 = detect_fp32(lniw);

  // ---- stage cx into LDS, fully coalesced (2 passes x 8 floats/thread) ----
  #pragma unroll
  for (int pass = 0; pass < 2; pass++) {
    int e = pass * 8192 + tid * 8;
    int r = e >> 10, c = e & 1023;
    float t[8];
    ld8(cx, (b0 + r) * H_ + c, t, fp32);
    *(float4*)&buf[r][c] = *(float4*)&t[0];
    *(float4*)&buf[r][c + 4] = *(float4*)&t[4];
  }

  // A-fragments for this block's 16 rows (shared by all waves)
  const ushort_t* xblk = xb + (size_t)blockIdx.x * 4096;
  bf8_t af[8];
  #pragma unroll
  for (int c = 0; c < 8; c++)
    af[c] = *(const bf8_t*)(xblk + c * 512 + lane * 8);

  float mi[4], mh[4];
  #pragma unroll
  for (int reg = 0; reg < 4; reg++) {
    mi[reg] = mrs_i[b0 + quad * 4 + reg];
    mh[reg] = mrs_h[b0 + quad * 4 + reg];
  }
  __syncthreads();

  float val[4][4], okeep[4][4];

  #pragma unroll
  for (int q = 0; q < 4; q++) {
    int cg = w * 4 + q;
    int col = cg * 16 + lcol;
    f4_t accg[4];
    #pragma unroll
    for (int g = 0; g < 4; g++) {
      f4_t acc = {0.f, 0.f, 0.f, 0.f};
      int t = g * 64 + cg;
      const ushort_t* wt = wb + (size_t)t * 4096 + lane * 8;
      #pragma unroll
      for (int c = 0; c < 8; c++) {
        bf8_t bf = *(const bf8_t*)(wt + c * 512);
        acc = __builtin_amdgcn_mfma_f32_16x16x32_bf16(af[c], bf, acc, 0, 0, 0);
      }
      accg[g] = acc;
    }
    float liw0 = ldf(lniw, 0 * H_ + col, fp32), lib0 = ldf(lnib, 0 * H_ + col, fp32);
    float lhw0 = ldf(lnhw, 0 * H_ + col, fp32), lhb0 = ldf(lnhb, 0 * H_ + col, fp32);
    float liw1 = ldf(lniw, 1 * H_ + col, fp32), lib1 = ldf(lnib, 1 * H_ + col, fp32);
    float lhw1 = ldf(lnhw, 1 * H_ + col, fp32), lhb1 = ldf(lnhb, 1 * H_ + col, fp32);
    float liw2 = ldf(lniw, 2 * H_ + col, fp32), lib2 = ldf(lnib, 2 * H_ + col, fp32);
    float lhw2 = ldf(lnhw, 2 * H_ + col, fp32), lhb2 = ldf(lnhb, 2 * H_ + col, fp32);
    float liw3 = ldf(lniw, 3 * H_ + col, fp32), lib3 = ldf(lnib, 3 * H_ + col, fp32);
    float lhw3 = ldf(lnhw, 3 * H_ + col, fp32), lhb3 = ldf(lnhb, 3 * H_ + col, fp32);
    #pragma unroll
    for (int reg = 0; reg < 4; reg++) {
      int m = quad * 4 + reg;
      float gi = accg[0][reg] + lib0 + lhb0 - mi[reg] * liw0 - mh[reg] * lhw0;
      float gf = accg[1][reg] + lib1 + lhb1 - mi[reg] * liw1 - mh[reg] * lhw1;
      float gg = accg[2][reg] + lib2 + lhb2 - mi[reg] * liw2 - mh[reg] * lhw2;
      float go = accg[3][reg] + lib3 + lhb3 - mi[reg] * liw3 - mh[reg] * lhw3;
      float iv = sigf(gi), fv = sigf(gf), gv = tanh_f(gg), ov = sigf(go);
      float cxv = buf[m][col];
      val[q][reg] = fv * cxv + iv * gv;
      okeep[q][reg] = ov;
    }
  }

  // cy-LN stats
  float s1[4] = {}, s2[4] = {};
  #pragma unroll
  for (int q = 0; q < 4; q++)
    #pragma unroll
    for (int reg = 0; reg < 4; reg++) {
      s1[reg] += val[q][reg];
      s2[reg] += val[q][reg] * val[q][reg];
    }
  #pragma unroll
  for (int d = 1; d < 16; d <<= 1) {
    #pragma unroll
    for (int reg = 0; reg < 4; reg++) {
      s1[reg] += __shfl_xor(s1[reg], d, 64);
      s2[reg] += __shfl_xor(s2[reg], d, 64);
    }
  }
  if (lcol == 0) {
    #pragma unroll
    for (int reg = 0; reg < 4; reg++) {
      wpart[w][quad * 4 + reg][0] = s1[reg];
      wpart[w][quad * 4 + reg][1] = s2[reg];
    }
  }
  __syncthreads();
  if (tid < 16) {
    float t1 = 0.f, t2 = 0.f;
    #pragma unroll
    for (int ww = 0; ww < 16; ww++) { t1 += wpart[ww][tid][0]; t2 += wpart[ww][tid][1]; }
    float mu = t1 * (1.0f / 1024.0f);
    float var = t2 * (1.0f / 1024.0f) - mu * mu;
    mu_s[tid] = mu;
    rs_s[tid] = rsqrtf(var + EPS_);
  }
  __syncthreads();

  // compute cy into buf (MFMA layout), keep hy in regs
  #pragma unroll
  for (int q = 0; q < 4; q++) {
    int col = (w * 4 + q) * 16 + lcol;
    float lw = ldf(lncw, col, fp32), lb = ldf(lncb, col, fp32);
    #pragma unroll
    for (int reg = 0; reg < 4; reg++) {
      int m = quad * 4 + reg;
      float cyv = (val[q][reg] - mu_s[m]) * rs_s[m] * lw + lb;
      buf[m][col] = cyv;
      val[q][reg] = okeep[q][reg] * tanh_f(cyv);   // hy
    }
  }
  __syncthreads();
  // store cy coalesced
  #pragma unroll
  for (int pass = 0; pass < 2; pass++) {
    int e = pass * 8192 + tid * 8;
    int r = e >> 10, c = e & 1023;
    float4 v0 = *(const float4*)&buf[r][c];
    float4 v1 = *(const float4*)&buf[r][c + 4];
    *(float4*)&out[(size_t)B_ * H_ + (b0 + r) * H_ + c] = v0;
    *(float4*)&out[(size_t)B_ * H_ + (b0 + r) * H_ + c + 4] = v1;
  }
  __syncthreads();
  // stage hy into buf
  #pragma unroll
  for (int q = 0; q < 4; q++) {
    int col = (w * 4 + q) * 16 + lcol;
    #pragma unroll
    for (int reg = 0; reg < 4; reg++)
      buf[quad * 4 + reg][col] = val[q][reg];
  }
  __syncthreads();
  // store hy coalesced
  #pragma unroll
  for (int pass = 0; pass < 2; pass++) {
    int e = pass * 8192 + tid * 8;
    int r = e >> 10, c = e & 1023;
    float4 v0 = *(const float4*)&buf[r][c];
    float4 v1 = *(const float4*)&buf[r][c + 4];
    *(float4*)&out[(b0 + r) * H_ + c] = v0;
    *(float4*)&out[(b0 + r) * H_ + c + 4] = v1;
  }
}

// ---------------------------------------------------------------------------
extern "C" void kernel_launch(void* const* d_in, const int* in_sizes, int n_in,
                              void* d_out, int out_size, void* d_ws, size_t ws_size,
                              hipStream_t stream) {
  const void* input_  = d_in[0];
  const void* hx      = d_in[1];
  const void* cx      = d_in[2];
  const void* topic   = d_in[3];
  const void* w_ih_a  = d_in[4];
  const void* w_ih_b  = d_in[5];
  const void* w_ih_c  = d_in[6];
  const void* w_hh_a  = d_in[7];
  const void* w_hh_b  = d_in[8];
  const void* w_hh_c  = d_in[9];
  const void* th_ih_w = d_in[10];
  const void* th_ih_b = d_in[11];
  const void* th_hh_w = d_in[12];
  const void* th_hh_b = d_in[13];
  const void* ln_i_w  = d_in[14];
  const void* ln_i_b  = d_in[15];
  const void* ln_h_w  = d_in[16];
  const void* ln_h_b  = d_in[17];
  const void* ln_c_w  = d_in[18];
  const void* ln_c_b  = d_in[19];

  float* w = (float*)d_ws;
  float* c1    = w;                          // B*F
  float* c2    = c1 + B_ * F_;
  float* g_i   = c2 + B_ * F_;               // F*F
  float* g_h   = g_i + F_ * F_;
  float* cm_i  = g_h + F_ * F_;              // F
  float* cm_h  = cm_i + F_;
  float* mrs_i = cm_h + F_;                  // B
  float* mrs_h = mrs_i + B_;
  ushort_t* xb = (ushort_t*)(mrs_h + B_);    // B*256 bf16 (A-frag order)
  ushort_t* wbf = xb + (size_t)B_ * 256;     // 256*4096 bf16 (B-frag order)

  hipMemsetAsync(g_i, 0, (size_t)(2 * F_ * F_ + 2 * F_) * sizeof(float), stream);

  k_stageA<<<dim3(NG1 + NPREP + NGRAM), dim3(256), 0, stream>>>(
      input_, hx, w_ih_c, w_hh_c, topic,
      th_ih_w, th_hh_w, th_ih_b, th_hh_b, w_ih_b, w_hh_b,
      w_ih_a, w_hh_a, ln_i_w, ln_h_w,
      wbf, cm_i, cm_h, g_i, g_h, c1, c2);
  k_stats2<<<dim3(512), dim3(256), 0, stream>>>(
      c1, c2, g_i, g_h, cm_i, cm_h, mrs_i, mrs_h, xb);
  k_fused<<<dim3(256), dim3(1024), 0, stream>>>(
      xb, wbf, mrs_i, mrs_h,
      ln_i_w, ln_i_b, ln_h_w, ln_h_b, ln_c_w, ln_c_b, cx, (float*)d_out);
}